// Round 5
// baseline (254.672 us; speedup 1.0000x reference)
//
#include <hip/hip_runtime.h>

#define HH 128

// ---------------- workspace layout (float offsets) ----------------
constexpr int OFF_AGGPL = 0;                        // P x H   (pl @ lines)
constexpr int OFF_AGGLP = OFF_AGGPL + 1024*HH;      // L x H   (pl.T @ points)
constexpr int OFF_AGGCP = OFF_AGGLP + 1024*HH;      // C x H   (pc.T @ points)
constexpr int OFF_MLPL  = OFF_AGGCP + 128*HH;       // 1024 masks
constexpr int OFF_MPLP  = OFF_MLPL + 1024;          // 1024
constexpr int OFF_MPCP  = OFF_MPLP + 1024;          // 128
constexpr int OFF_LPL   = OFF_MPCP + 128;           // 1024 x H
constexpr int OFF_PLP   = OFF_LPL + 1024*HH;        // 1024 x H
constexpr int OFF_PCP   = OFF_PLP + 1024*HH;        // 128 x H
constexpr int OFF_G1    = OFF_PCP + 128*HH;         // 4256 x H (gm layer 1)
constexpr int OFF_GT    = OFF_G1 + 4256*HH;         // 4256 x H (gm layer 2)
constexpr int OFF_BTEXT = OFF_GT + 4256*HH;         // 4256 x H
constexpr int OFF_BHEAD = OFF_BTEXT + 4256*HH;      // 3200 x H
constexpr int OFF_BANG  = OFF_BHEAD + 3200*HH;      // 1024 x H
constexpr int OFF_BBAR  = OFF_BANG + 1024*HH;       // 1024 x H
constexpr int OFF_BPARA = OFF_BBAR + 1024*HH;       // 1024 x H
constexpr int OFF_BPERP = OFF_BPARA + 1024*HH;      // 1024 x H
constexpr int OFF_A     = OFF_BPERP + 1024*HH;      // 288 x H  (sym @ W1.T + b1)
constexpr int WS_FLOATS = OFF_A + 288*HH;           // ~12.1 MiB

// ---------------- kernel 1: relation aggregations + masks ----------------
// blocks [0,128): aggPL rows (pl @ lines), [128,256): aggLP cols (pl.T @ points),
// [256,272): aggCP cols (pc.T @ points). 512 threads: h-quad = t&31, row = (t>>5)&7,
// K-half = t>>8. 8 output rows per block, K=1024 split in two 512 halves.
__global__ __launch_bounds__(512) void k_agg(
    const int* __restrict__ pl, const int* __restrict__ pc,
    const float* __restrict__ points, const float* __restrict__ lines,
    float* __restrict__ ws)
{
    __shared__ __attribute__((aligned(16))) float rel[8][1024];
    __shared__ __attribute__((aligned(16))) float4 red[8][32];
    const int t = threadIdx.x;
    const int b = blockIdx.x;
    const int hq = t & 31;
    const int r8 = (t >> 5) & 7;
    const int g  = t >> 8;     // 0/1

    const float* V; float* OUT; float* MASK; int base;
    if (b < 128) {
        base = b*8; V = lines; OUT = ws + OFF_AGGPL; MASK = ws + OFF_MLPL;
        const int4* pl4 = (const int4*)pl;
        #pragma unroll
        for (int i = 0; i < 4; ++i) {
            int idx = i*512 + t; int r = idx >> 8, lq = idx & 255;
            int4 v = pl4[(base + r)*256 + lq];
            float4 f; f.x=(float)v.x; f.y=(float)v.y; f.z=(float)v.z; f.w=(float)v.w;
            *(float4*)&rel[r][lq*4] = f;
        }
    } else if (b < 256) {
        base = (b-128)*8; V = points; OUT = ws + OFF_AGGLP; MASK = ws + OFF_MPLP;
        #pragma unroll
        for (int i = 0; i < 16; ++i) {
            int idx = i*512 + t; int c = idx & 7, k = idx >> 3;
            rel[c][k] = (float)pl[k*1024 + base + c];
        }
    } else {
        base = (b-256)*8; V = points; OUT = ws + OFF_AGGCP; MASK = ws + OFF_MPCP;
        #pragma unroll
        for (int i = 0; i < 16; ++i) {
            int idx = i*512 + t; int c = idx & 7, k = idx >> 3;
            rel[c][k] = (float)pc[k*128 + base + c];
        }
    }
    __syncthreads();
    {   // masks: one wave per row, rowsum >= 2
        int r = t >> 6, lane = t & 63;
        float s = 0.f;
        #pragma unroll
        for (int i = 0; i < 16; ++i) s += rel[r][lane*16 + i];
        #pragma unroll
        for (int off = 32; off; off >>= 1) s += __shfl_xor(s, off, 64);
        if (lane == 0) MASK[base + r] = (s >= 2.0f) ? 1.0f : 0.0f;
    }
    float4 acc = {0.f,0.f,0.f,0.f};
    const float4* V4 = (const float4*)V;
    const int l0 = g * 512;
    for (int l = l0; l < l0 + 512; l += 4) {
        float4 rv = *(const float4*)&rel[r8][l];   // wave-broadcast
        float4 v0 = V4[(l+0)*32 + hq];
        float4 v1 = V4[(l+1)*32 + hq];
        float4 v2 = V4[(l+2)*32 + hq];
        float4 v3 = V4[(l+3)*32 + hq];
        acc.x += rv.x*v0.x + rv.y*v1.x + rv.z*v2.x + rv.w*v3.x;
        acc.y += rv.x*v0.y + rv.y*v1.y + rv.z*v2.y + rv.w*v3.y;
        acc.z += rv.x*v0.z + rv.y*v1.z + rv.z*v2.z + rv.w*v3.z;
        acc.w += rv.x*v0.w + rv.y*v1.w + rv.z*v2.w + rv.w*v3.w;
    }
    if (g == 1) red[r8][hq] = acc;
    __syncthreads();
    if (g == 0) {
        float4 o = red[r8][hq];
        acc.x += o.x; acc.y += o.y; acc.z += o.z; acc.w += o.w;
        *(float4*)&OUT[(base + r8)*HH + hq*4] = acc;
    }
}

// ---------------- kernel 2: generic  OUT = [LN(relu(] X @ W.T + b [))*g+be]  ----------------
// mode 0: REL (X = 2*agg + middle, LRL) -> LPL/PLP/PCP
// mode 1: GM layer1 on gathered geo_t rows (LRL) -> G1
// mode 2: GM layer2 on G1 (LRL) -> GT
// mode 3: projections (no relu/LN): six B matrices + A (sym proj, +bias)
// 256 threads, 32 rows/block, thread tile 4 rows x 4 cols; W staged transposed
// in LDS in two 64-h halves to stay under the 64KB static-LDS cap.
__global__ __launch_bounds__(256) void k_lrl(
    int mode, float* __restrict__ ws,
    const float* __restrict__ points, const float* __restrict__ lines,
    const float* __restrict__ circles, const float* __restrict__ text_s,
    const float* __restrict__ head_s, const float* __restrict__ angle_s,
    const float* __restrict__ bar_s, const float* __restrict__ para_s,
    const float* __restrict__ perp_s,
    const float* __restrict__ rel_W, const float* __restrict__ rel_b,
    const float* __restrict__ rel_g, const float* __restrict__ rel_be,
    const float* __restrict__ gm_W, const float* __restrict__ gm_b,
    const float* __restrict__ gm_g, const float* __restrict__ gm_be,
    const float* __restrict__ sc_W1, const float* __restrict__ sc_b1)
{
    __shared__ __attribute__((aligned(16))) float Xs[32][132];
    __shared__ __attribute__((aligned(16))) float Ws[64][132];   // Ws[h][j] = W[j][h]
    const int t = threadIdx.x;
    const int row0 = blockIdx.x * 32;

    const float* W = nullptr; const float* bias = nullptr;
    const float* gv = nullptr; const float* bev = nullptr;
    const float* xsrc = nullptr; const float* asrc = nullptr; const float* msrc = nullptr;
    float* outp = nullptr;
    bool do_ln = false;

    if (mode == 0) {
        do_ln = true;
        if (row0 < 1024) {
            asrc = ws + OFF_AGGPL + row0*HH; msrc = points + row0*HH;
            W = rel_W;          bias = rel_b;       gv = rel_g;       bev = rel_be;
            outp = ws + OFF_LPL + row0*HH;
        } else if (row0 < 2048) {
            int r = row0 - 1024;
            asrc = ws + OFF_AGGLP + r*HH; msrc = lines + r*HH;
            W = rel_W + 16384;  bias = rel_b + 128; gv = rel_g + 128; bev = rel_be + 128;
            outp = ws + OFF_PLP + r*HH;
        } else {
            int r = row0 - 2048;
            asrc = ws + OFF_AGGCP + r*HH; msrc = circles + r*HH;
            W = rel_W + 32768;  bias = rel_b + 256; gv = rel_g + 256; bev = rel_be + 256;
            outp = ws + OFF_PCP + r*HH;
        }
    } else if (mode == 1) {
        do_ln = true; W = gm_W; bias = gm_b; gv = gm_g; bev = gm_be;
        outp = ws + OFF_G1 + row0*HH;
        if      (row0 < 1024) xsrc = points + row0*HH;
        else if (row0 < 2048) xsrc = lines + (row0-1024)*HH;
        else if (row0 < 3072) xsrc = ws + OFF_LPL + (row0-2048)*HH;
        else if (row0 < 4096) xsrc = ws + OFF_PLP + (row0-3072)*HH;
        else if (row0 < 4224) xsrc = ws + OFF_PCP + (row0-4096)*HH;
        else                  xsrc = head_s + (row0-4224)*HH;
    } else if (mode == 2) {
        do_ln = true; W = gm_W + 16384; bias = gm_b + 128; gv = gm_g + 128; bev = gm_be + 128;
        xsrc = ws + OFF_G1 + row0*HH;
        outp = ws + OFF_GT + row0*HH;
    } else {
        do_ln = false;
        if (row0 < 4256) {
            xsrc = ws + OFF_GT + row0*HH; W = sc_W1; outp = ws + OFF_BTEXT + row0*HH;
        } else if (row0 < 7456) {
            int i0 = row0 - 4256;
            W = sc_W1 + 16384; outp = ws + OFF_BHEAD + i0*HH;
            int gtrow;
            if      (i0 < 1024) gtrow = i0;                    // points
            else if (i0 < 2048) gtrow = 2048 + (i0 - 1024);    // LPL
            else if (i0 < 3072) gtrow = 3072 + (i0 - 2048);    // PLP
            else                gtrow = 4096 + (i0 - 3072);    // PCP
            xsrc = ws + OFF_GT + gtrow*HH;
        } else if (row0 < 8480) {
            int i0 = row0 - 7456;
            xsrc = ws + OFF_LPL + i0*HH; W = sc_W1 + 2*16384; outp = ws + OFF_BANG + i0*HH;
        } else if (row0 < 9504) {
            int i0 = row0 - 8480;
            xsrc = ws + OFF_PLP + i0*HH; W = sc_W1 + 3*16384; outp = ws + OFF_BBAR + i0*HH;
        } else if (row0 < 10528) {
            int i0 = row0 - 9504;
            xsrc = lines + i0*HH;        W = sc_W1 + 4*16384; outp = ws + OFF_BPARA + i0*HH;
        } else if (row0 < 11552) {
            int i0 = row0 - 10528;
            xsrc = ws + OFF_LPL + i0*HH; W = sc_W1 + 5*16384; outp = ws + OFF_BPERP + i0*HH;
        } else {
            int i0 = row0 - 11552;
            outp = ws + OFF_A + i0*HH;
            int k; const float* s;
            if      (i0 < 64)  { k=0; s = text_s  + i0*HH; }
            else if (i0 < 96)  { k=1; s = head_s  + (i0-64)*HH; }
            else if (i0 < 160) { k=2; s = angle_s + (i0-96)*HH; }
            else if (i0 < 224) { k=3; s = bar_s   + (i0-160)*HH; }
            else if (i0 < 256) { k=4; s = para_s  + (i0-224)*HH; }
            else               { k=5; s = perp_s  + (i0-256)*HH; }
            xsrc = s; W = sc_W1 + k*16384; bias = sc_b1 + k*128;
        }
    }

    // stage X rows (32 x 128)
    if (asrc != nullptr) {
        #pragma unroll
        for (int i = 0; i < 4; ++i) {
            int idx = i*256 + t; int r = idx >> 5, hq = idx & 31;
            float4 a = *(const float4*)&asrc[r*HH + hq*4];
            float4 m = *(const float4*)&msrc[r*HH + hq*4];
            float4 v; v.x = 2.f*a.x+m.x; v.y = 2.f*a.y+m.y; v.z = 2.f*a.z+m.z; v.w = 2.f*a.w+m.w;
            *(float4*)&Xs[r][hq*4] = v;
        }
    } else {
        #pragma unroll
        for (int i = 0; i < 4; ++i) {
            int idx = i*256 + t; int r = idx >> 5, hq = idx & 31;
            *(float4*)&Xs[r][hq*4] = *(const float4*)&xsrc[r*HH + hq*4];
        }
    }

    const int jq = t & 31;    // j = jq*4
    const int rq = t >> 5;    // rows rq*4 .. +3
    float acc[4][4] = {};
    for (int p = 0; p < 2; ++p) {
        __syncthreads();
        // stage W half transposed: Ws[hh][j] = W[j][p*64+hh]
        #pragma unroll
        for (int i = 0; i < 8; ++i) {
            int idx = i*256 + t; int j = idx >> 4, hq = idx & 15;
            float4 v = *(const float4*)&W[j*HH + p*64 + hq*4];
            Ws[hq*4+0][j] = v.x; Ws[hq*4+1][j] = v.y; Ws[hq*4+2][j] = v.z; Ws[hq*4+3][j] = v.w;
        }
        __syncthreads();
        #pragma unroll
        for (int hh = 0; hh < 64; hh += 4) {
            const int h = p*64 + hh;
            float4 x0 = *(const float4*)&Xs[rq*4+0][h];
            float4 x1 = *(const float4*)&Xs[rq*4+1][h];
            float4 x2 = *(const float4*)&Xs[rq*4+2][h];
            float4 x3 = *(const float4*)&Xs[rq*4+3][h];
            float4 w0 = *(const float4*)&Ws[hh+0][jq*4];
            float4 w1 = *(const float4*)&Ws[hh+1][jq*4];
            float4 w2 = *(const float4*)&Ws[hh+2][jq*4];
            float4 w3 = *(const float4*)&Ws[hh+3][jq*4];
            #define ROWUPD(ri, xv) \
                acc[ri][0] += xv.x*w0.x + xv.y*w1.x + xv.z*w2.x + xv.w*w3.x; \
                acc[ri][1] += xv.x*w0.y + xv.y*w1.y + xv.z*w2.y + xv.w*w3.y; \
                acc[ri][2] += xv.x*w0.z + xv.y*w1.z + xv.z*w2.z + xv.w*w3.z; \
                acc[ri][3] += xv.x*w0.w + xv.y*w1.w + xv.z*w2.w + xv.w*w3.w;
            ROWUPD(0, x0) ROWUPD(1, x1) ROWUPD(2, x2) ROWUPD(3, x3)
            #undef ROWUPD
        }
    }

    float4 bv = {0.f,0.f,0.f,0.f};
    if (bias != nullptr) bv = *(const float4*)&bias[jq*4];
    if (do_ln) {
        float4 gg = *(const float4*)&gv[jq*4];
        float4 bb = *(const float4*)&bev[jq*4];
        #pragma unroll
        for (int ri = 0; ri < 4; ++ri) {
            float y0 = fmaxf(acc[ri][0] + bv.x, 0.f);
            float y1 = fmaxf(acc[ri][1] + bv.y, 0.f);
            float y2 = fmaxf(acc[ri][2] + bv.z, 0.f);
            float y3 = fmaxf(acc[ri][3] + bv.w, 0.f);
            float s1 = y0+y1+y2+y3;
            float s2 = y0*y0+y1*y1+y2*y2+y3*y3;
            #pragma unroll
            for (int off = 16; off; off >>= 1) {
                s1 += __shfl_xor(s1, off, 32);
                s2 += __shfl_xor(s2, off, 32);
            }
            float m   = s1 * (1.0f/128.0f);
            float var = s2 * (1.0f/128.0f) - m*m;
            float sc  = rsqrtf(var + 1e-5f);
            float4 o;
            o.x = (y0 - m)*sc*gg.x + bb.x;
            o.y = (y1 - m)*sc*gg.y + bb.y;
            o.z = (y2 - m)*sc*gg.z + bb.z;
            o.w = (y3 - m)*sc*gg.w + bb.w;
            *(float4*)&outp[(rq*4+ri)*HH + jq*4] = o;
        }
    } else {
        #pragma unroll
        for (int ri = 0; ri < 4; ++ri) {
            float4 o;
            o.x = acc[ri][0] + bv.x; o.y = acc[ri][1] + bv.y;
            o.z = acc[ri][2] + bv.z; o.w = acc[ri][3] + bv.w;
            *(float4*)&outp[(rq*4+ri)*HH + jq*4] = o;
        }
    }
}

// ---------------- kernel 3: pairwise scoring ----------------
// logit[n,r] = (sum_j y*gw2 - mean(y)*sum(gw2)) * rsqrt(var(y)+eps) + (sum be*W2 + b2)
// with y = relu(A[n]+B[r]). 16x16 pair tile per block, one pair per thread.
__global__ __launch_bounds__(256) void k_score(
    const float* __restrict__ ws,
    const float* __restrict__ sc_g, const float* __restrict__ sc_be,
    const float* __restrict__ sc_W2, const float* __restrict__ sc_b2,
    float* __restrict__ out)
{
    __shared__ __attribute__((aligned(16))) float As[16][132];
    __shared__ __attribute__((aligned(16))) float Bs[16][132];
    __shared__ __attribute__((aligned(16))) float gw2s[128];
    __shared__ float msk[16];
    __shared__ float red2[4];
    const int t = threadIdx.x, b = blockIdx.x;
    int k, tn, tr, Rk, Abase, outbase;
    const float* Bk;
    if (b < 1064)      { k=0; int lc=b;      tn=lc/266; tr=lc%266; Rk=4256; Abase=0;   outbase=0;      Bk = ws+OFF_BTEXT; }
    else if (b < 1464) { k=1; int lc=b-1064; tn=lc/200; tr=lc%200; Rk=3200; Abase=64;  outbase=272384; Bk = ws+OFF_BHEAD; }
    else if (b < 1720) { k=2; int lc=b-1464; tn=lc>>6;  tr=lc&63;  Rk=1024; Abase=96;  outbase=374784; Bk = ws+OFF_BANG; }
    else if (b < 1976) { k=3; int lc=b-1720; tn=lc>>6;  tr=lc&63;  Rk=1024; Abase=160; outbase=440320; Bk = ws+OFF_BBAR; }
    else if (b < 2104) { k=4; int lc=b-1976; tn=lc>>6;  tr=lc&63;  Rk=1024; Abase=224; outbase=505856; Bk = ws+OFF_BPARA; }
    else               { k=5; int lc=b-2104; tn=lc>>6;  tr=lc&63;  Rk=1024; Abase=256; outbase=538624; Bk = ws+OFF_BPERP; }

    if (t < 128) {
        float g = sc_g[k*128+t], w2 = sc_W2[k*128+t], be = sc_be[k*128+t];
        float gw = g*w2, bw = be*w2;
        gw2s[t] = gw;
        #pragma unroll
        for (int off = 32; off; off >>= 1) {
            gw += __shfl_xor(gw, off, 64);
            bw += __shfl_xor(bw, off, 64);
        }
        if ((t & 63) == 0) { red2[(t>>6)*2+0] = gw; red2[(t>>6)*2+1] = bw; }
    }
    const float* Ap = ws + OFF_A + (Abase + tn*16)*HH;
    const float* Bp = Bk + tr*16*HH;
    #pragma unroll
    for (int i = 0; i < 2; ++i) {
        int idx = i*256 + t; int r = idx >> 5, hq = idx & 31;
        *(float4*)&As[r][hq*4] = *(const float4*)&Ap[r*HH + hq*4];
        *(float4*)&Bs[r][hq*4] = *(const float4*)&Bp[r*HH + hq*4];
    }
    if (t < 16) {
        int r = tr*16 + t;
        float mv = 1.0f;
        const float* mL = ws + OFF_MLPL;
        const float* mP = ws + OFF_MPLP;
        const float* mC = ws + OFF_MPCP;
        if (k == 0) {
            if      (r >= 2048 && r < 3072) mv = mL[r-2048];
            else if (r >= 3072 && r < 4096) mv = mP[r-3072];
            else if (r >= 4096 && r < 4224) mv = mC[r-4096];
        } else if (k == 1) {
            if      (r >= 1024 && r < 2048) mv = mL[r-1024];
            else if (r >= 2048 && r < 3072) mv = mP[r-2048];
            else if (r >= 3072)             mv = mC[r-3072];
        } else if (k == 2 || k == 5) mv = mL[r];
        else if (k == 3)             mv = mP[r];
        msk[t] = mv;
    }
    __syncthreads();
    const float sgw2 = red2[0] + red2[2];
    const float cb   = red2[1] + red2[3] + sc_b2[k];
    const int ni = t >> 4, ri = t & 15;
    float s1 = 0.f, s2 = 0.f, sw = 0.f;
    #pragma unroll
    for (int h = 0; h < 128; h += 4) {
        float4 av = *(const float4*)&As[ni][h];
        float4 bv = *(const float4*)&Bs[ri][h];
        float4 wv = *(const float4*)&gw2s[h];
        float y;
        y = fmaxf(av.x + bv.x, 0.f); s1 += y; s2 += y*y; sw += y*wv.x;
        y = fmaxf(av.y + bv.y, 0.f); s1 += y; s2 += y*y; sw += y*wv.y;
        y = fmaxf(av.z + bv.z, 0.f); s1 += y; s2 += y*y; sw += y*wv.z;
        y = fmaxf(av.w + bv.w, 0.f); s1 += y; s2 += y*y; sw += y*wv.w;
    }
    float m   = s1 * (1.0f/128.0f);
    float var = s2 * (1.0f/128.0f) - m*m;
    float logit = (sw - m*sgw2) * rsqrtf(var + 1e-5f) + cb;
    float o = (msk[ri] > 0.f) ? (1.0f/(1.0f + __expf(-logit))) : 0.0f;
    out[outbase + (tn*16+ni)*Rk + tr*16 + ri] = o;
}

// ---------------- launch ----------------
extern "C" void kernel_launch(void* const* d_in, const int* in_sizes, int n_in,
                              void* d_out, int out_size, void* d_ws, size_t ws_size,
                              hipStream_t stream)
{
    const float* points  = (const float*)d_in[0];
    const float* lines   = (const float*)d_in[1];
    const float* circles = (const float*)d_in[2];
    const float* text_s  = (const float*)d_in[3];
    const float* head_s  = (const float*)d_in[4];
    const float* angle_s = (const float*)d_in[5];
    const float* bar_s   = (const float*)d_in[6];
    const float* para_s  = (const float*)d_in[7];
    const float* perp_s  = (const float*)d_in[8];
    const float* rel_W   = (const float*)d_in[9];
    const float* rel_b   = (const float*)d_in[10];
    const float* rel_g   = (const float*)d_in[11];
    const float* rel_be  = (const float*)d_in[12];
    const float* gm_W    = (const float*)d_in[13];
    const float* gm_b    = (const float*)d_in[14];
    const float* gm_g    = (const float*)d_in[15];
    const float* gm_be   = (const float*)d_in[16];
    const float* sc_W1   = (const float*)d_in[17];
    const float* sc_b1   = (const float*)d_in[18];
    const float* sc_g    = (const float*)d_in[19];
    const float* sc_be   = (const float*)d_in[20];
    const float* sc_W2   = (const float*)d_in[21];
    const float* sc_b2   = (const float*)d_in[22];
    const int*   pl      = (const int*)d_in[23];
    const int*   pc      = (const int*)d_in[24];
    float* ws  = (float*)d_ws;
    float* out = (float*)d_out;
    if (ws_size < (size_t)WS_FLOATS * sizeof(float)) return;  // visible failure, no corruption

    hipLaunchKernelGGL(k_agg, dim3(272), dim3(512), 0, stream, pl, pc, points, lines, ws);
    #define LRL_ARGS ws, points, lines, circles, text_s, head_s, angle_s, bar_s, para_s, perp_s, \
        rel_W, rel_b, rel_g, rel_be, gm_W, gm_b, gm_g, gm_be, sc_W1, sc_b1
    hipLaunchKernelGGL(k_lrl, dim3(68),  dim3(256), 0, stream, 0, LRL_ARGS);
    hipLaunchKernelGGL(k_lrl, dim3(133), dim3(256), 0, stream, 1, LRL_ARGS);
    hipLaunchKernelGGL(k_lrl, dim3(133), dim3(256), 0, stream, 2, LRL_ARGS);
    hipLaunchKernelGGL(k_lrl, dim3(370), dim3(256), 0, stream, 3, LRL_ARGS);
    #undef LRL_ARGS
    hipLaunchKernelGGL(k_score, dim3(2232), dim3(256), 0, stream, ws, sc_g, sc_be, sc_W2, sc_b2, out);
}

// Round 9
// 194.681 us; speedup vs baseline: 1.3082x; 1.3082x over previous
//
#include <hip/hip_runtime.h>

#define HH 128

// ---------------- workspace layout (float offsets) ----------------
constexpr int OFF_AGGPL = 0;                        // P x H   (pl @ lines)
constexpr int OFF_AGGLP = OFF_AGGPL + 1024*HH;      // L x H   (pl.T @ points)
constexpr int OFF_AGGCP = OFF_AGGLP + 1024*HH;      // C x H   (pc.T @ points)
constexpr int OFF_MLPL  = OFF_AGGCP + 128*HH;       // 1024 masks
constexpr int OFF_MPLP  = OFF_MLPL + 1024;          // 1024
constexpr int OFF_MPCP  = OFF_MPLP + 1024;          // 128
constexpr int OFF_LPL   = OFF_MPCP + 128;           // 1024 x H
constexpr int OFF_PLP   = OFF_LPL + 1024*HH;        // 1024 x H
constexpr int OFF_PCP   = OFF_PLP + 1024*HH;        // 128 x H
constexpr int OFF_G1    = OFF_PCP + 128*HH;         // 4256 x H (gm layer 1)
constexpr int OFF_GT    = OFF_G1 + 4256*HH;         // 4256 x H (gm layer 2)
constexpr int OFF_BTEXT = OFF_GT + 4256*HH;         // 4256 x H
constexpr int OFF_BHEAD = OFF_BTEXT + 4256*HH;      // 3200 x H
constexpr int OFF_BANG  = OFF_BHEAD + 3200*HH;      // 1024 x H
constexpr int OFF_BBAR  = OFF_BANG + 1024*HH;       // 1024 x H
constexpr int OFF_BPARA = OFF_BBAR + 1024*HH;       // 1024 x H
constexpr int OFF_BPERP = OFF_BPARA + 1024*HH;      // 1024 x H
constexpr int OFF_A     = OFF_BPERP + 1024*HH;      // 288 x H  (sym @ W1.T + b1)
constexpr int WS_FLOATS = OFF_A + 288*HH;           // ~12.1 MiB

// ---------------- kernel 1: relation aggregations + masks ----------------
// blocks [0,128): aggPL rows (pl @ lines), [128,256): aggLP cols (pl.T @ points),
// [256,272): aggCP cols (pc.T @ points). 8 output rows per block.
// Full-reuse redesign (R5): each 32-lane group owns a distinct K-range of 64
// (16-way in-block split-K); each thread accumulates ALL 8 rows (acc[8][4]).
// V (points/lines) is read exactly once per block (was 16x redundant -> L2
// latency bound, VALUBusy 5%). Partials flat-reduced via 64KB LDS aliased
// over the dead rel tile.
__global__ __launch_bounds__(512) void k_agg(
    const int* __restrict__ pl, const int* __restrict__ pc,
    const float* __restrict__ points, const float* __restrict__ lines,
    float* __restrict__ ws)
{
    __shared__ __attribute__((aligned(16))) float smem[16384];   // 64 KB
    float (*rel)[1024] = (float(*)[1024])smem;   // staging view: rel[8][1024] (32 KB)
    float* red = smem;                            // reduce view: red[16][8][128] (64 KB)
    const int t = threadIdx.x;
    const int b = blockIdx.x;
    const int hq  = t & 31;    // h-quad: cols hq*4..+3
    const int grp = t >> 5;    // 0..15: K-range [grp*64, grp*64+64)

    const float* V; float* OUT; float* MASK; int base;
    if (b < 128) {
        base = b*8; V = lines; OUT = ws + OFF_AGGPL; MASK = ws + OFF_MLPL;
        const int4* pl4 = (const int4*)pl;
        #pragma unroll
        for (int i = 0; i < 4; ++i) {
            int idx = i*512 + t; int r = idx >> 8, lq = idx & 255;
            int4 v = pl4[(base + r)*256 + lq];
            float4 f; f.x=(float)v.x; f.y=(float)v.y; f.z=(float)v.z; f.w=(float)v.w;
            *(float4*)&rel[r][lq*4] = f;
        }
    } else if (b < 256) {
        base = (b-128)*8; V = points; OUT = ws + OFF_AGGLP; MASK = ws + OFF_MPLP;
        #pragma unroll
        for (int i = 0; i < 16; ++i) {
            int idx = i*512 + t; int c = idx & 7, k = idx >> 3;
            rel[c][k] = (float)pl[k*1024 + base + c];
        }
    } else {
        base = (b-256)*8; V = points; OUT = ws + OFF_AGGCP; MASK = ws + OFF_MPCP;
        #pragma unroll
        for (int i = 0; i < 16; ++i) {
            int idx = i*512 + t; int c = idx & 7, k = idx >> 3;
            rel[c][k] = (float)pc[k*128 + base + c];
        }
    }
    __syncthreads();
    {   // masks: one wave per row, rowsum >= 2
        int r = t >> 6, lane = t & 63;
        float s = 0.f;
        #pragma unroll
        for (int i = 0; i < 16; ++i) s += rel[r][lane*16 + i];
        #pragma unroll
        for (int off = 32; off; off >>= 1) s += __shfl_xor(s, off, 64);
        if (lane == 0) MASK[base + r] = (s >= 2.0f) ? 1.0f : 0.0f;
    }

    float4 acc[8];
    #pragma unroll
    for (int r = 0; r < 8; ++r) acc[r] = {0.f, 0.f, 0.f, 0.f};
    const float4* V4 = (const float4*)V;
    const int l0 = grp * 64;
    #pragma unroll 4
    for (int l = l0; l < l0 + 64; l += 4) {
        float4 v0 = V4[(l+0)*32 + hq];
        float4 v1 = V4[(l+1)*32 + hq];
        float4 v2 = V4[(l+2)*32 + hq];
        float4 v3 = V4[(l+3)*32 + hq];
        #pragma unroll
        for (int r = 0; r < 8; ++r) {
            float4 rv = *(const float4*)&rel[r][l];   // broadcast within half-wave
            acc[r].x += rv.x*v0.x + rv.y*v1.x + rv.z*v2.x + rv.w*v3.x;
            acc[r].y += rv.x*v0.y + rv.y*v1.y + rv.z*v2.y + rv.w*v3.y;
            acc[r].z += rv.x*v0.z + rv.y*v1.z + rv.z*v2.z + rv.w*v3.z;
            acc[r].w += rv.x*v0.w + rv.y*v1.w + rv.z*v2.w + rv.w*v3.w;
        }
    }
    __syncthreads();   // rel dead; reuse smem as red
    #pragma unroll
    for (int r = 0; r < 8; ++r)
        *(float4*)&red[(grp*8 + r)*128 + hq*4] = acc[r];
    __syncthreads();
    // flat 16-way reduce: 2 outputs per thread, conflict-free (2-way max)
    #pragma unroll
    for (int o = t; o < 1024; o += 512) {
        int r = o >> 7, c = o & 127;
        float s = 0.f;
        #pragma unroll
        for (int g2 = 0; g2 < 16; ++g2) s += red[g2*1024 + r*128 + c];
        OUT[(base + r)*HH + c] = s;
    }
}

// ---------------- kernel 2: generic  OUT = [LN(relu(] X @ W.T + b [))*g+be]  ----------------
// mode 0: REL (X = 2*agg + middle, LRL) -> LPL/PLP/PCP
// mode 1: GM layer1 on gathered geo_t rows (LRL) -> G1
// mode 2: GM layer2 on G1 (LRL) -> GT
// mode 3: projections (no relu/LN): six B matrices + A (sym proj, +bias)
// 256 threads, 32 rows/block, thread tile 4 rows x 4 cols; W staged transposed
// in LDS in two 64-h halves to stay under the 64KB static-LDS cap.
__global__ __launch_bounds__(256) void k_lrl(
    int mode, float* __restrict__ ws,
    const float* __restrict__ points, const float* __restrict__ lines,
    const float* __restrict__ circles, const float* __restrict__ text_s,
    const float* __restrict__ head_s, const float* __restrict__ angle_s,
    const float* __restrict__ bar_s, const float* __restrict__ para_s,
    const float* __restrict__ perp_s,
    const float* __restrict__ rel_W, const float* __restrict__ rel_b,
    const float* __restrict__ rel_g, const float* __restrict__ rel_be,
    const float* __restrict__ gm_W, const float* __restrict__ gm_b,
    const float* __restrict__ gm_g, const float* __restrict__ gm_be,
    const float* __restrict__ sc_W1, const float* __restrict__ sc_b1)
{
    __shared__ __attribute__((aligned(16))) float Xs[32][132];
    __shared__ __attribute__((aligned(16))) float Ws[64][132];   // Ws[h][j] = W[j][h]
    const int t = threadIdx.x;
    const int row0 = blockIdx.x * 32;

    const float* W = nullptr; const float* bias = nullptr;
    const float* gv = nullptr; const float* bev = nullptr;
    const float* xsrc = nullptr; const float* asrc = nullptr; const float* msrc = nullptr;
    float* outp = nullptr;
    bool do_ln = false;

    if (mode == 0) {
        do_ln = true;
        if (row0 < 1024) {
            asrc = ws + OFF_AGGPL + row0*HH; msrc = points + row0*HH;
            W = rel_W;          bias = rel_b;       gv = rel_g;       bev = rel_be;
            outp = ws + OFF_LPL + row0*HH;
        } else if (row0 < 2048) {
            int r = row0 - 1024;
            asrc = ws + OFF_AGGLP + r*HH; msrc = lines + r*HH;
            W = rel_W + 16384;  bias = rel_b + 128; gv = rel_g + 128; bev = rel_be + 128;
            outp = ws + OFF_PLP + r*HH;
        } else {
            int r = row0 - 2048;
            asrc = ws + OFF_AGGCP + r*HH; msrc = circles + r*HH;
            W = rel_W + 32768;  bias = rel_b + 256; gv = rel_g + 256; bev = rel_be + 256;
            outp = ws + OFF_PCP + r*HH;
        }
    } else if (mode == 1) {
        do_ln = true; W = gm_W; bias = gm_b; gv = gm_g; bev = gm_be;
        outp = ws + OFF_G1 + row0*HH;
        if      (row0 < 1024) xsrc = points + row0*HH;
        else if (row0 < 2048) xsrc = lines + (row0-1024)*HH;
        else if (row0 < 3072) xsrc = ws + OFF_LPL + (row0-2048)*HH;
        else if (row0 < 4096) xsrc = ws + OFF_PLP + (row0-3072)*HH;
        else if (row0 < 4224) xsrc = ws + OFF_PCP + (row0-4096)*HH;
        else                  xsrc = head_s + (row0-4224)*HH;
    } else if (mode == 2) {
        do_ln = true; W = gm_W + 16384; bias = gm_b + 128; gv = gm_g + 128; bev = gm_be + 128;
        xsrc = ws + OFF_G1 + row0*HH;
        outp = ws + OFF_GT + row0*HH;
    } else {
        do_ln = false;
        if (row0 < 4256) {
            xsrc = ws + OFF_GT + row0*HH; W = sc_W1; outp = ws + OFF_BTEXT + row0*HH;
        } else if (row0 < 7456) {
            int i0 = row0 - 4256;
            W = sc_W1 + 16384; outp = ws + OFF_BHEAD + i0*HH;
            int gtrow;
            if      (i0 < 1024) gtrow = i0;                    // points
            else if (i0 < 2048) gtrow = 2048 + (i0 - 1024);    // LPL
            else if (i0 < 3072) gtrow = 3072 + (i0 - 2048);    // PLP
            else                gtrow = 4096 + (i0 - 3072);    // PCP
            xsrc = ws + OFF_GT + gtrow*HH;
        } else if (row0 < 8480) {
            int i0 = row0 - 7456;
            xsrc = ws + OFF_LPL + i0*HH; W = sc_W1 + 2*16384; outp = ws + OFF_BANG + i0*HH;
        } else if (row0 < 9504) {
            int i0 = row0 - 8480;
            xsrc = ws + OFF_PLP + i0*HH; W = sc_W1 + 3*16384; outp = ws + OFF_BBAR + i0*HH;
        } else if (row0 < 10528) {
            int i0 = row0 - 9504;
            xsrc = lines + i0*HH;        W = sc_W1 + 4*16384; outp = ws + OFF_BPARA + i0*HH;
        } else if (row0 < 11552) {
            int i0 = row0 - 10528;
            xsrc = ws + OFF_LPL + i0*HH; W = sc_W1 + 5*16384; outp = ws + OFF_BPERP + i0*HH;
        } else {
            int i0 = row0 - 11552;
            outp = ws + OFF_A + i0*HH;
            int k; const float* s;
            if      (i0 < 64)  { k=0; s = text_s  + i0*HH; }
            else if (i0 < 96)  { k=1; s = head_s  + (i0-64)*HH; }
            else if (i0 < 160) { k=2; s = angle_s + (i0-96)*HH; }
            else if (i0 < 224) { k=3; s = bar_s   + (i0-160)*HH; }
            else if (i0 < 256) { k=4; s = para_s  + (i0-224)*HH; }
            else               { k=5; s = perp_s  + (i0-256)*HH; }
            xsrc = s; W = sc_W1 + k*16384; bias = sc_b1 + k*128;
        }
    }

    // stage X rows (32 x 128)
    if (asrc != nullptr) {
        #pragma unroll
        for (int i = 0; i < 4; ++i) {
            int idx = i*256 + t; int r = idx >> 5, hq = idx & 31;
            float4 a = *(const float4*)&asrc[r*HH + hq*4];
            float4 m = *(const float4*)&msrc[r*HH + hq*4];
            float4 v; v.x = 2.f*a.x+m.x; v.y = 2.f*a.y+m.y; v.z = 2.f*a.z+m.z; v.w = 2.f*a.w+m.w;
            *(float4*)&Xs[r][hq*4] = v;
        }
    } else {
        #pragma unroll
        for (int i = 0; i < 4; ++i) {
            int idx = i*256 + t; int r = idx >> 5, hq = idx & 31;
            *(float4*)&Xs[r][hq*4] = *(const float4*)&xsrc[r*HH + hq*4];
        }
    }

    const int jq = t & 31;    // j = jq*4
    const int rq = t >> 5;    // rows rq*4 .. +3
    float acc[4][4] = {};
    for (int p = 0; p < 2; ++p) {
        __syncthreads();
        // stage W half transposed: Ws[hh][j] = W[j][p*64+hh]
        #pragma unroll
        for (int i = 0; i < 8; ++i) {
            int idx = i*256 + t; int j = idx >> 4, hq = idx & 15;
            float4 v = *(const float4*)&W[j*HH + p*64 + hq*4];
            Ws[hq*4+0][j] = v.x; Ws[hq*4+1][j] = v.y; Ws[hq*4+2][j] = v.z; Ws[hq*4+3][j] = v.w;
        }
        __syncthreads();
        #pragma unroll
        for (int hh = 0; hh < 64; hh += 4) {
            const int h = p*64 + hh;
            float4 x0 = *(const float4*)&Xs[rq*4+0][h];
            float4 x1 = *(const float4*)&Xs[rq*4+1][h];
            float4 x2 = *(const float4*)&Xs[rq*4+2][h];
            float4 x3 = *(const float4*)&Xs[rq*4+3][h];
            float4 w0 = *(const float4*)&Ws[hh+0][jq*4];
            float4 w1 = *(const float4*)&Ws[hh+1][jq*4];
            float4 w2 = *(const float4*)&Ws[hh+2][jq*4];
            float4 w3 = *(const float4*)&Ws[hh+3][jq*4];
            #define ROWUPD(ri, xv) \
                acc[ri][0] += xv.x*w0.x + xv.y*w1.x + xv.z*w2.x + xv.w*w3.x; \
                acc[ri][1] += xv.x*w0.y + xv.y*w1.y + xv.z*w2.y + xv.w*w3.y; \
                acc[ri][2] += xv.x*w0.z + xv.y*w1.z + xv.z*w2.z + xv.w*w3.z; \
                acc[ri][3] += xv.x*w0.w + xv.y*w1.w + xv.z*w2.w + xv.w*w3.w;
            ROWUPD(0, x0) ROWUPD(1, x1) ROWUPD(2, x2) ROWUPD(3, x3)
            #undef ROWUPD
        }
    }

    float4 bv = {0.f,0.f,0.f,0.f};
    if (bias != nullptr) bv = *(const float4*)&bias[jq*4];
    if (do_ln) {
        float4 gg = *(const float4*)&gv[jq*4];
        float4 bb = *(const float4*)&bev[jq*4];
        #pragma unroll
        for (int ri = 0; ri < 4; ++ri) {
            float y0 = fmaxf(acc[ri][0] + bv.x, 0.f);
            float y1 = fmaxf(acc[ri][1] + bv.y, 0.f);
            float y2 = fmaxf(acc[ri][2] + bv.z, 0.f);
            float y3 = fmaxf(acc[ri][3] + bv.w, 0.f);
            float s1 = y0+y1+y2+y3;
            float s2 = y0*y0+y1*y1+y2*y2+y3*y3;
            #pragma unroll
            for (int off = 16; off; off >>= 1) {
                s1 += __shfl_xor(s1, off, 32);
                s2 += __shfl_xor(s2, off, 32);
            }
            float m   = s1 * (1.0f/128.0f);
            float var = s2 * (1.0f/128.0f) - m*m;
            float sc  = rsqrtf(var + 1e-5f);
            float4 o;
            o.x = (y0 - m)*sc*gg.x + bb.x;
            o.y = (y1 - m)*sc*gg.y + bb.y;
            o.z = (y2 - m)*sc*gg.z + bb.z;
            o.w = (y3 - m)*sc*gg.w + bb.w;
            *(float4*)&outp[(rq*4+ri)*HH + jq*4] = o;
        }
    } else {
        #pragma unroll
        for (int ri = 0; ri < 4; ++ri) {
            float4 o;
            o.x = acc[ri][0] + bv.x; o.y = acc[ri][1] + bv.y;
            o.z = acc[ri][2] + bv.z; o.w = acc[ri][3] + bv.w;
            *(float4*)&outp[(rq*4+ri)*HH + jq*4] = o;
        }
    }
}

// ---------------- kernel 3: pairwise scoring ----------------
// logit[n,r] = (sum_j y*gw2 - mean(y)*sum(gw2)) * rsqrt(var(y)+eps) + (sum be*W2 + b2)
// with y = relu(A[n]+B[r]). 16x16 pair tile per block, one pair per thread.
__global__ __launch_bounds__(256) void k_score(
    const float* __restrict__ ws,
    const float* __restrict__ sc_g, const float* __restrict__ sc_be,
    const float* __restrict__ sc_W2, const float* __restrict__ sc_b2,
    float* __restrict__ out)
{
    __shared__ __attribute__((aligned(16))) float As[16][132];
    __shared__ __attribute__((aligned(16))) float Bs[16][132];
    __shared__ __attribute__((aligned(16))) float gw2s[128];
    __shared__ float msk[16];
    __shared__ float red2[4];
    const int t = threadIdx.x, b = blockIdx.x;
    int k, tn, tr, Rk, Abase, outbase;
    const float* Bk;
    if (b < 1064)      { k=0; int lc=b;      tn=lc/266; tr=lc%266; Rk=4256; Abase=0;   outbase=0;      Bk = ws+OFF_BTEXT; }
    else if (b < 1464) { k=1; int lc=b-1064; tn=lc/200; tr=lc%200; Rk=3200; Abase=64;  outbase=272384; Bk = ws+OFF_BHEAD; }
    else if (b < 1720) { k=2; int lc=b-1464; tn=lc>>6;  tr=lc&63;  Rk=1024; Abase=96;  outbase=374784; Bk = ws+OFF_BANG; }
    else if (b < 1976) { k=3; int lc=b-1720; tn=lc>>6;  tr=lc&63;  Rk=1024; Abase=160; outbase=440320; Bk = ws+OFF_BBAR; }
    else if (b < 2104) { k=4; int lc=b-1976; tn=lc>>6;  tr=lc&63;  Rk=1024; Abase=224; outbase=505856; Bk = ws+OFF_BPARA; }
    else               { k=5; int lc=b-2104; tn=lc>>6;  tr=lc&63;  Rk=1024; Abase=256; outbase=538624; Bk = ws+OFF_BPERP; }

    if (t < 128) {
        float g = sc_g[k*128+t], w2 = sc_W2[k*128+t], be = sc_be[k*128+t];
        float gw = g*w2, bw = be*w2;
        gw2s[t] = gw;
        #pragma unroll
        for (int off = 32; off; off >>= 1) {
            gw += __shfl_xor(gw, off, 64);
            bw += __shfl_xor(bw, off, 64);
        }
        if ((t & 63) == 0) { red2[(t>>6)*2+0] = gw; red2[(t>>6)*2+1] = bw; }
    }
    const float* Ap = ws + OFF_A + (Abase + tn*16)*HH;
    const float* Bp = Bk + tr*16*HH;
    #pragma unroll
    for (int i = 0; i < 2; ++i) {
        int idx = i*256 + t; int r = idx >> 5, hq = idx & 31;
        *(float4*)&As[r][hq*4] = *(const float4*)&Ap[r*HH + hq*4];
        *(float4*)&Bs[r][hq*4] = *(const float4*)&Bp[r*HH + hq*4];
    }
    if (t < 16) {
        int r = tr*16 + t;
        float mv = 1.0f;
        const float* mL = ws + OFF_MLPL;
        const float* mP = ws + OFF_MPLP;
        const float* mC = ws + OFF_MPCP;
        if (k == 0) {
            if      (r >= 2048 && r < 3072) mv = mL[r-2048];
            else if (r >= 3072 && r < 4096) mv = mP[r-3072];
            else if (r >= 4096 && r < 4224) mv = mC[r-4096];
        } else if (k == 1) {
            if      (r >= 1024 && r < 2048) mv = mL[r-1024];
            else if (r >= 2048 && r < 3072) mv = mP[r-2048];
            else if (r >= 3072)             mv = mC[r-3072];
        } else if (k == 2 || k == 5) mv = mL[r];
        else if (k == 3)             mv = mP[r];
        msk[t] = mv;
    }
    __syncthreads();
    const float sgw2 = red2[0] + red2[2];
    const float cb   = red2[1] + red2[3] + sc_b2[k];
    const int ni = t >> 4, ri = t & 15;
    float s1 = 0.f, s2 = 0.f, sw = 0.f;
    #pragma unroll
    for (int h = 0; h < 128; h += 4) {
        float4 av = *(const float4*)&As[ni][h];
        float4 bv = *(const float4*)&Bs[ri][h];
        float4 wv = *(const float4*)&gw2s[h];
        float y;
        y = fmaxf(av.x + bv.x, 0.f); s1 += y; s2 += y*y; sw += y*wv.x;
        y = fmaxf(av.y + bv.y, 0.f); s1 += y; s2 += y*y; sw += y*wv.y;
        y = fmaxf(av.z + bv.z, 0.f); s1 += y; s2 += y*y; sw += y*wv.z;
        y = fmaxf(av.w + bv.w, 0.f); s1 += y; s2 += y*y; sw += y*wv.w;
    }
    float m   = s1 * (1.0f/128.0f);
    float var = s2 * (1.0f/128.0f) - m*m;
    float logit = (sw - m*sgw2) * rsqrtf(var + 1e-5f) + cb;
    float o = (msk[ri] > 0.f) ? (1.0f/(1.0f + __expf(-logit))) : 0.0f;
    out[outbase + (tn*16+ni)*Rk + tr*16 + ri] = o;
}

// ---------------- launch ----------------
extern "C" void kernel_launch(void* const* d_in, const int* in_sizes, int n_in,
                              void* d_out, int out_size, void* d_ws, size_t ws_size,
                              hipStream_t stream)
{
    const float* points  = (const float*)d_in[0];
    const float* lines   = (const float*)d_in[1];
    const float* circles = (const float*)d_in[2];
    const float* text_s  = (const float*)d_in[3];
    const float* head_s  = (const float*)d_in[4];
    const float* angle_s = (const float*)d_in[5];
    const float* bar_s   = (const float*)d_in[6];
    const float* para_s  = (const float*)d_in[7];
    const float* perp_s  = (const float*)d_in[8];
    const float* rel_W   = (const float*)d_in[9];
    const float* rel_b   = (const float*)d_in[10];
    const float* rel_g   = (const float*)d_in[11];
    const float* rel_be  = (const float*)d_in[12];
    const float* gm_W    = (const float*)d_in[13];
    const float* gm_b    = (const float*)d_in[14];
    const float* gm_g    = (const float*)d_in[15];
    const float* gm_be   = (const float*)d_in[16];
    const float* sc_W1   = (const float*)d_in[17];
    const float* sc_b1   = (const float*)d_in[18];
    const float* sc_g    = (const float*)d_in[19];
    const float* sc_be   = (const float*)d_in[20];
    const float* sc_W2   = (const float*)d_in[21];
    const float* sc_b2   = (const float*)d_in[22];
    const int*   pl      = (const int*)d_in[23];
    const int*   pc      = (const int*)d_in[24];
    float* ws  = (float*)d_ws;
    float* out = (float*)d_out;
    if (ws_size < (size_t)WS_FLOATS * sizeof(float)) return;  // visible failure, no corruption

    hipLaunchKernelGGL(k_agg, dim3(272), dim3(512), 0, stream, pl, pc, points, lines, ws);
    #define LRL_ARGS ws, points, lines, circles, text_s, head_s, angle_s, bar_s, para_s, perp_s, \
        rel_W, rel_b, rel_g, rel_be, gm_W, gm_b, gm_g, gm_be, sc_W1, sc_b1
    hipLaunchKernelGGL(k_lrl, dim3(68),  dim3(256), 0, stream, 0, LRL_ARGS);
    hipLaunchKernelGGL(k_lrl, dim3(133), dim3(256), 0, stream, 1, LRL_ARGS);
    hipLaunchKernelGGL(k_lrl, dim3(133), dim3(256), 0, stream, 2, LRL_ARGS);
    hipLaunchKernelGGL(k_lrl, dim3(370), dim3(256), 0, stream, 3, LRL_ARGS);
    #undef LRL_ARGS
    hipLaunchKernelGGL(k_score, dim3(2232), dim3(256), 0, stream, ws, sc_g, sc_be, sc_W2, sc_b2, out);
}